// Round 1
// baseline (330.805 us; speedup 1.0000x reference)
//
#include <hip/hip_runtime.h>

// ---------------------------------------------------------------------------
// PositionEncoder: per token (B*T = 262144), output 272 f32:
//   x[0:6] | emb[idx1] (128) | x[6:10] | emb[idx2] (128) | x[10:16]
// idx from matching (x[4],x[5]) / (x[8],x[9]) vs 26 nodes,
// close iff |p - node| <= 0.01 + 1e-5*|node| per dim; idx = first match + 1.
// Memory-bound: 16 MiB read + 272 MiB write; emb (51 KB) is cache-resident.
// ---------------------------------------------------------------------------

#define TOK_PER_BLOCK 64
#define THREADS 256

// Node coordinates (constexpr so the unrolled compare loop folds them, and
// thresholds, to immediates at compile time with exact IEEE f32 semantics).
constexpr float kNX[26] = {
    0.5454545454545454f, 0.6022727272727273f, 0.5454545454545454f,
    0.6022727272727273f, 0.4772727272727273f, 0.42045454545454547f,
    0.42045454545454547f, 0.4772727272727273f, 0.32954545454545453f,
    0.42045454545454547f, 0.4772727272727273f, 0.4772727272727273f,
    0.42045454545454547f, 0.32954545454545453f, 0.5727272727272728f,
    0.7613636363636364f, 0.8181818181818182f, 0.8181818181818182f,
    0.7613636363636364f, 0.7909090909090909f, 0.9431818181818182f,
    1.0f, 1.0f, 0.9431818181818182f, 0.9727272727272728f, 0.9727272727272728f};
constexpr float kNY[26] = {
    0.76f, 0.76f, 0.86f, 0.86f, 0.76f, 0.76f, 0.86f, 0.86f, 0.808f,
    0.48f, 0.48f, 0.38f, 0.38f, 0.428f, 0.62f, 0.76f, 0.76f, 0.86f,
    0.86f, 0.62f, 0.76f, 0.76f, 0.86f, 0.86f, 0.62f, 1.0f};

__device__ __forceinline__ int point_index(float px, float py) {
#pragma clang fp contract(off)
    int idx = 0;
    // Reverse iterate + overwrite => lowest-index match wins (== argmax of
    // boolean). Nodes are >atol apart so at most one matches anyway.
#pragma unroll
    for (int n = 25; n >= 0; --n) {
        float tx = 0.01f + 1.0e-5f * kNX[n];   // folds at compile time
        float ty = 0.01f + 1.0e-5f * kNY[n];
        bool c = (fabsf(px - kNX[n]) <= tx) && (fabsf(py - kNY[n]) <= ty);
        if (c) idx = n + 1;
    }
    return idx;
}

__global__ __launch_bounds__(THREADS) void pos_enc_kernel(
    const float* __restrict__ x, const float* __restrict__ emb,
    float* __restrict__ out, int n_tokens) {
    __shared__ float xs[TOK_PER_BLOCK * 16];         // 4 KB
    __shared__ int   sidx[2 * TOK_PER_BLOCK];        // idx1 | idx2

    const int tid  = threadIdx.x;
    const int tok0 = blockIdx.x * TOK_PER_BLOCK;

    // ---- stage x tile: 64 tokens * 16 f32 = 256 float4 (fully coalesced) ----
    {
        long long g4     = (long long)blockIdx.x * THREADS + tid;  // float4 idx
        long long total4 = (long long)n_tokens * 4;
        if (g4 < total4) {
            ((float4*)xs)[tid] = ((const float4*)x)[g4];
        }
    }
    __syncthreads();

    // ---- compute node indices: thread t<128 -> token t&63, point (t>>6) ----
    if (tid < 2 * TOK_PER_BLOCK) {
        int t     = tid & (TOK_PER_BLOCK - 1);
        int which = tid >> 6;                      // 0 -> col 4, 1 -> col 8
        if (tok0 + t < n_tokens) {
            int col  = which ? 8 : 4;
            float px = xs[t * 16 + col];
            float py = xs[t * 16 + col + 1];
            sidx[which * TOK_PER_BLOCK + t] = point_index(px, py);
        }
    }
    __syncthreads();

    // ---- write 272 f32 = 68 float4 per token; block = 4352 contiguous f4 ----
    const long long out4_base  = (long long)tok0 * 68;
    const long long total_out4 = (long long)n_tokens * 68;
    for (int it = 0; it < (TOK_PER_BLOCK * 68) / THREADS + 1; ++it) {
        int l = it * THREADS + tid;                 // local vec4 index [0,4352)
        if (l >= TOK_PER_BLOCK * 68) break;
        long long g = out4_base + l;
        if (g >= total_out4) break;
        int lt = l / 68;                            // local token
        int v  = l - lt * 68;                       // vec4 within token
        int c0 = v * 4;                             // first column of this vec4
        const float* xr = &xs[lt * 16];
        int i1 = sidx[lt];
        int i2 = sidx[TOK_PER_BLOCK + lt];
        float vals[4];
#pragma unroll
        for (int j = 0; j < 4; ++j) {
            int c = c0 + j;
            float val;
            if (c < 6)        val = xr[c];                        // x[0:6]
            else if (c < 134) val = emb[i1 * 128 + (c - 6)];      // emb row 1
            else if (c < 138) val = xr[c - 128];                  // x[6:10]
            else if (c < 266) val = emb[i2 * 128 + (c - 138)];    // emb row 2
            else              val = xr[c - 256];                  // x[10:16]
            vals[j] = val;
        }
        float4 o = make_float4(vals[0], vals[1], vals[2], vals[3]);
        ((float4*)out)[g] = o;
    }
}

extern "C" void kernel_launch(void* const* d_in, const int* in_sizes, int n_in,
                              void* d_out, int out_size, void* d_ws, size_t ws_size,
                              hipStream_t stream) {
    const float* x   = (const float*)d_in[0];   // [B, T, 16] f32
    const float* emb = (const float*)d_in[1];   // [100, 128] f32
    float* out = (float*)d_out;                 // [B, T, 272] f32

    int n_tokens = in_sizes[0] / 16;            // 128*2048 = 262144
    int nblocks  = (n_tokens + TOK_PER_BLOCK - 1) / TOK_PER_BLOCK;

    pos_enc_kernel<<<nblocks, THREADS, 0, stream>>>(x, emb, out, n_tokens);
}

// Round 2
// 311.223 us; speedup vs baseline: 1.0629x; 1.0629x over previous
//
#include <hip/hip_runtime.h>

// ---------------------------------------------------------------------------
// PositionEncoder: per token (B*T = 262144), output 272 f32:
//   x[0:6] | emb[idx1] (128) | x[6:10] | emb[idx2] (128) | x[10:16]
// idx from matching (x[4],x[5]) / (x[8],x[9]) vs 26 nodes,
// close iff |p - node| <= 0.01 + 1e-5*|node| per dim; idx = first match + 1.
//
// R1 post-mortem: per-element branchy gather => latency-bound (~2 TB/s eff).
// R2: build the 32x272 output tile in LDS with uniform control flow, then
// stream it to global as pure coalesced float4 stores.
// ---------------------------------------------------------------------------

#define TOK 32          // tokens per block
#define THREADS 256

constexpr float kNX[26] = {
    0.5454545454545454f, 0.6022727272727273f, 0.5454545454545454f,
    0.6022727272727273f, 0.4772727272727273f, 0.42045454545454547f,
    0.42045454545454547f, 0.4772727272727273f, 0.32954545454545453f,
    0.42045454545454547f, 0.4772727272727273f, 0.4772727272727273f,
    0.42045454545454547f, 0.32954545454545453f, 0.5727272727272728f,
    0.7613636363636364f, 0.8181818181818182f, 0.8181818181818182f,
    0.7613636363636364f, 0.7909090909090909f, 0.9431818181818182f,
    1.0f, 1.0f, 0.9431818181818182f, 0.9727272727272728f, 0.9727272727272728f};
constexpr float kNY[26] = {
    0.76f, 0.76f, 0.86f, 0.86f, 0.76f, 0.76f, 0.86f, 0.86f, 0.808f,
    0.48f, 0.48f, 0.38f, 0.38f, 0.428f, 0.62f, 0.76f, 0.76f, 0.86f,
    0.86f, 0.62f, 0.76f, 0.76f, 0.86f, 0.86f, 0.62f, 1.0f};

__device__ __forceinline__ int point_index(float px, float py) {
#pragma clang fp contract(off)
    int idx = 0;
    // Reverse iterate + overwrite => lowest-index match wins.
#pragma unroll
    for (int n = 25; n >= 0; --n) {
        float tx = 0.01f + 1.0e-5f * kNX[n];   // compile-time folded
        float ty = 0.01f + 1.0e-5f * kNY[n];
        bool c = (fabsf(px - kNX[n]) <= tx) && (fabsf(py - kNY[n]) <= ty);
        if (c) idx = n + 1;
    }
    return idx;
}

__global__ __launch_bounds__(THREADS) void pos_enc_kernel(
    const float* __restrict__ x, const float* __restrict__ emb,
    float* __restrict__ out, int n_tokens) {
    __shared__ float xs[TOK * 16];          // 2 KB  staged x tile
    __shared__ int   sidx[2 * TOK];         // node indices
    __shared__ float ot[TOK * 272];         // 34 KB output tile

    const int tid  = threadIdx.x;
    const int tok0 = blockIdx.x * TOK;
    const int ntok = min(TOK, n_tokens - tok0);   // tokens valid in this block

    // ---- stage x tile: 32 tokens * 16 f32 = 128 float4 (coalesced) ----
    if (tid < TOK * 4) {
        long long g4 = (long long)tok0 * 4 + tid;
        if (g4 < (long long)n_tokens * 4)
            ((float4*)xs)[tid] = ((const float4*)x)[g4];
    }
    __syncthreads();

    // ---- node indices: thread t<64 -> token t&31, point (t>>5) ----
    if (tid < 2 * TOK) {
        int t     = tid & (TOK - 1);
        int which = tid >> 5;                 // 0 -> cols 4,5 ; 1 -> cols 8,9
        if (t < ntok) {
            int col  = which ? 8 : 4;
            sidx[which * TOK + t] =
                point_index(xs[t * 16 + col], xs[t * 16 + col + 1]);
        }
    }
    __syncthreads();

    // ---- fill output tile in LDS (uniform control flow) ----
    // (a) x-derived columns: 16 per token, 512 total -> 2 rounds
    for (int i = tid; i < TOK * 16; i += THREADS) {
        int t = i >> 4, c = i & 15;
        int dst = (c < 6) ? c : ((c < 10) ? c + 128 : c + 256);
        ot[t * 272 + dst] = xs[i];
    }
    // (b) emb rows as float2 (dst offsets 6 and 138 floats are 8B-aligned):
    //     32 tokens * 2 rows * 64 float2 = 4096 -> 16 rounds, reads L1-hot
    for (int i = tid; i < TOK * 2 * 64; i += THREADS) {
        int t     = i >> 7;
        int r     = i & 127;
        int which = r >> 6;
        int f2    = r & 63;
        int idx   = sidx[which * TOK + t];
        float2 v  = ((const float2*)emb)[idx * 64 + f2];
        int dstf  = t * 272 + (which ? 138 : 6) + f2 * 2;
        *(float2*)&ot[dstf] = v;
    }
    __syncthreads();

    // ---- stream tile to global: pure coalesced float4 copy ----
    const long long out4_base = (long long)tok0 * 68;
    const int nvec4 = ntok * 68;              // 2176 when full
    for (int l = tid; l < nvec4; l += THREADS) {
        ((float4*)out)[out4_base + l] = ((const float4*)ot)[l];
    }
}

extern "C" void kernel_launch(void* const* d_in, const int* in_sizes, int n_in,
                              void* d_out, int out_size, void* d_ws, size_t ws_size,
                              hipStream_t stream) {
    const float* x   = (const float*)d_in[0];   // [B, T, 16] f32
    const float* emb = (const float*)d_in[1];   // [100, 128] f32
    float* out = (float*)d_out;                 // [B, T, 272] f32

    int n_tokens = in_sizes[0] / 16;            // 262144
    int nblocks  = (n_tokens + TOK - 1) / TOK;  // 8192

    pos_enc_kernel<<<nblocks, THREADS, 0, stream>>>(x, emb, out, n_tokens);
}

// Round 4
// 307.481 us; speedup vs baseline: 1.0759x; 1.0122x over previous
//
#include <hip/hip_runtime.h>

// ---------------------------------------------------------------------------
// PositionEncoder: per token (B*T = 262144), output 272 f32:
//   x[0:6] | emb[idx1] (128) | x[6:10] | emb[idx2] (128) | x[10:16]
// idx from matching (x[4],x[5]) / (x[8],x[9]) vs 26 nodes,
// close iff |p - node| <= 0.01 + 1e-5*|node| per dim; idx = first match + 1.
//
// R1: branchy per-element gather => latency-bound, kernel ~145 us.
// R2: LDS output tile + coalesced float4 stream => ~126 us. Counter model
//     shows ~2.3 TB/s effective store BW == write-allocate reads of every
//     output line (fills show FETCH~0 because they store non-temporally).
// R3: nt store on HIP float4 struct doesn't compile -> R4 uses a clang
//     ext_vector_type(4) float for __builtin_nontemporal_store.
// ---------------------------------------------------------------------------

#define TOK 32          // tokens per block
#define THREADS 256

typedef float vfloat4 __attribute__((ext_vector_type(4)));  // native vector

constexpr float kNX[26] = {
    0.5454545454545454f, 0.6022727272727273f, 0.5454545454545454f,
    0.6022727272727273f, 0.4772727272727273f, 0.42045454545454547f,
    0.42045454545454547f, 0.4772727272727273f, 0.32954545454545453f,
    0.42045454545454547f, 0.4772727272727273f, 0.4772727272727273f,
    0.42045454545454547f, 0.32954545454545453f, 0.5727272727272728f,
    0.7613636363636364f, 0.8181818181818182f, 0.8181818181818182f,
    0.7613636363636364f, 0.7909090909090909f, 0.9431818181818182f,
    1.0f, 1.0f, 0.9431818181818182f, 0.9727272727272728f, 0.9727272727272728f};
constexpr float kNY[26] = {
    0.76f, 0.76f, 0.86f, 0.86f, 0.76f, 0.76f, 0.86f, 0.86f, 0.808f,
    0.48f, 0.48f, 0.38f, 0.38f, 0.428f, 0.62f, 0.76f, 0.76f, 0.86f,
    0.86f, 0.62f, 0.76f, 0.76f, 0.86f, 0.86f, 0.62f, 1.0f};

__device__ __forceinline__ int point_index(float px, float py) {
#pragma clang fp contract(off)
    int idx = 0;
    // Reverse iterate + overwrite => lowest-index match wins.
#pragma unroll
    for (int n = 25; n >= 0; --n) {
        float tx = 0.01f + 1.0e-5f * kNX[n];   // compile-time folded
        float ty = 0.01f + 1.0e-5f * kNY[n];
        bool c = (fabsf(px - kNX[n]) <= tx) && (fabsf(py - kNY[n]) <= ty);
        if (c) idx = n + 1;
    }
    return idx;
}

__global__ __launch_bounds__(THREADS) void pos_enc_kernel(
    const float* __restrict__ x, const float* __restrict__ emb,
    float* __restrict__ out, int n_tokens) {
    __shared__ float xs[TOK * 16];          // 2 KB  staged x tile
    __shared__ int   sidx[2 * TOK];         // node indices
    __shared__ float ot[TOK * 272];         // 34 KB output tile

    const int tid  = threadIdx.x;
    const int tok0 = blockIdx.x * TOK;
    const int ntok = min(TOK, n_tokens - tok0);   // tokens valid in this block

    // ---- stage x tile: 32 tokens * 16 f32 = 128 float4 (coalesced) ----
    if (tid < TOK * 4) {
        long long g4 = (long long)tok0 * 4 + tid;
        if (g4 < (long long)n_tokens * 4)
            ((vfloat4*)xs)[tid] = ((const vfloat4*)x)[g4];
    }
    __syncthreads();

    // ---- node indices: thread t<64 -> token t&31, point (t>>5) ----
    if (tid < 2 * TOK) {
        int t     = tid & (TOK - 1);
        int which = tid >> 5;                 // 0 -> cols 4,5 ; 1 -> cols 8,9
        if (t < ntok) {
            int col  = which ? 8 : 4;
            sidx[which * TOK + t] =
                point_index(xs[t * 16 + col], xs[t * 16 + col + 1]);
        }
    }
    __syncthreads();

    // ---- fill output tile in LDS (uniform control flow) ----
    // (a) x-derived columns: 16 per token, 512 total -> 2 rounds
    for (int i = tid; i < TOK * 16; i += THREADS) {
        int t = i >> 4, c = i & 15;
        int dst = (c < 6) ? c : ((c < 10) ? c + 128 : c + 256);
        ot[t * 272 + dst] = xs[i];
    }
    // (b) emb rows as float2 (dst offsets 6 and 138 floats are 8B-aligned):
    //     32 tokens * 2 rows * 64 float2 = 4096 -> 16 rounds, reads L2-hot
    for (int i = tid; i < TOK * 2 * 64; i += THREADS) {
        int t     = i >> 7;
        int r     = i & 127;
        int which = r >> 6;
        int f2    = r & 63;
        int idx   = sidx[which * TOK + t];
        float2 v  = ((const float2*)emb)[idx * 64 + f2];
        int dstf  = t * 272 + (which ? 138 : 6) + f2 * 2;
        *(float2*)&ot[dstf] = v;
    }
    __syncthreads();

    // ---- stream tile to global: coalesced NON-TEMPORAL float4 stores ----
    // Output is write-once, never re-read: nt stores skip the write-allocate
    // read of each output line (the 285 MB phantom FETCH seen in R2).
    const long long out4_base = (long long)tok0 * 68;
    const int nvec4 = ntok * 68;              // 2176 when full
    for (int l = tid; l < nvec4; l += THREADS) {
        vfloat4 v = ((const vfloat4*)ot)[l];
        __builtin_nontemporal_store(v, &((vfloat4*)out)[out4_base + l]);
    }
}

extern "C" void kernel_launch(void* const* d_in, const int* in_sizes, int n_in,
                              void* d_out, int out_size, void* d_ws, size_t ws_size,
                              hipStream_t stream) {
    const float* x   = (const float*)d_in[0];   // [B, T, 16] f32
    const float* emb = (const float*)d_in[1];   // [100, 128] f32
    float* out = (float*)d_out;                 // [B, T, 272] f32

    int n_tokens = in_sizes[0] / 16;            // 262144
    int nblocks  = (n_tokens + TOK - 1) / TOK;  // 8192

    pos_enc_kernel<<<nblocks, THREADS, 0, stream>>>(x, emb, out, n_tokens);
}